// Round 5
// baseline (36.544 us; speedup 1.0000x reference)
//
#include <hip/hip_runtime.h>
#include <hip/hip_bf16.h>

// ThreeWayAttention: B=32, S=128, D=32, F=32, U=11
// p_ijk ∝ EA[i,j]·EB[j,k]·EC[i,k], EX = exp(X/9), diagonals = 0.
// job0 (chunk cc over j, κ-quarter kq over k): acc[i,κ]=Σ_j EA[i,j]EB[j,κ];
//   v = EC[i,κ]·acc → m1 partial (row sums), m3 partial (col sums)
// job1 (chunk cc over i): acc[j,κ]=Σ_i EA[i,j]EC[i,κ]; v = EB[j,κ]·acc → m2
// Unified: At[c][r] = exp(dot(QA[r],QC[c])/9)   (0 if r==c0+c)
//          Bs[c][κ] = exp(dot(QC[c],QK[κ])/9)   (0 if kq0+κ==c0+c)
//          W[r][κ]  = exp(dot(QA[r],QK[κ])/9)   (0 if r==kq0+κ)
// job0: QA=Q1, QC=Q2, QK=Q3.  job1: QA=Q2, QC=Q1, QK=Q3.
// out = [m1@V, m2@V, m3@V]/Z, Z = Σ m1.

#define B_ 32
#define S_ 128
#define D_ 32
#define F_ 32
#define U_ 11
#define INV9 (1.0f / 9.0f)

__global__ __launch_bounds__(256, 4) void k_fused(
    const float* __restrict__ X,
    const float* __restrict__ W1, const float* __restrict__ b1,
    const float* __restrict__ W2, const float* __restrict__ b2,
    const float* __restrict__ W3, const float* __restrict__ b3,
    float* __restrict__ m1p, float* __restrict__ m2p, float* __restrict__ m3p) {
    int bid = blockIdx.x;
    int b   = bid & 31;
    int job = (bid >> 5) & 1;
    int cc  = (bid >> 6) & 3;
    int kq  = bid >> 8;               // 0..3
    int c0  = cc * 32, kq0 = kq * 32;
    int t = threadIdx.x;

    // pool aliases: phase1 Wt[3][U_][32] (1056 fl) -> phase3+ At[32][132]
    // (4224 fl) -> phase7 red[4][32] (128 fl)
    __shared__ float pool[32 * 132];
    __shared__ float Bs[32][36];
    __shared__ float QAt[U_][S_];
    __shared__ float QKt[U_][32];
    __shared__ float QCt[U_][32];
    __shared__ float bsh[3][U_];
    float* At = pool;
    float* Wt = pool;                 // Wt[(m*U_+u)*32 + d]
    float* red = pool;                // red[w*32 + k]

    // ---- phase 1: stage W^T + biases ----
    for (int idx = t; idx < 3 * U_ * D_; idx += 256) {
        int m = idx / (U_ * D_), r = idx - m * (U_ * D_);
        int u = r >> 5, d = r & 31;
        const float* Wm = (m == 0) ? W1 : (m == 1) ? W2 : W3;
        Wt[idx] = Wm[d * U_ + u];
    }
    if (t < 3 * U_) {
        int m = t / U_, u = t - m * U_;
        const float* bm = (m == 0) ? b1 : (m == 1) ? b2 : b3;
        bsh[m][u] = bm[u];
    }
    __syncthreads();

    // ---- phase 2: Q projections ----
    // t<128: QA rows 0..127 (mat=job). 128..159: QK rows kq0+.. (mat 2).
    // 160..191: QC rows c0+.. (mat 1-job). 192..255 idle.
    if (t < 192) {
        int grp = (t < 128) ? 0 : (t < 160) ? 1 : 2;
        int row = (grp == 0) ? t : (grp == 1) ? (kq0 + t - 128) : (c0 + t - 160);
        int mat = (grp == 0) ? job : (grp == 1) ? 2 : (1 - job);
        const float* Xrow = X + ((size_t)b * S_ + row) * D_;
        float4 xv[8];
#pragma unroll
        for (int q = 0; q < 8; ++q) xv[q] = ((const float4*)Xrow)[q];
        float qv[U_];
#pragma unroll
        for (int u = 0; u < U_; ++u) qv[u] = bsh[mat][u];
#pragma unroll
        for (int d4 = 0; d4 < 8; ++d4) {
            float4 x = xv[d4];
#pragma unroll
            for (int u = 0; u < U_; ++u) {
                float4 w = *(const float4*)&Wt[(mat * U_ + u) * 32 + d4 * 4];
                qv[u] += x.x * w.x + x.y * w.y + x.z * w.z + x.w * w.w;
            }
        }
        if (grp == 0) {
#pragma unroll
            for (int u = 0; u < U_; ++u) QAt[u][t] = qv[u];
        } else if (grp == 1) {
#pragma unroll
            for (int u = 0; u < U_; ++u) QKt[u][t - 128] = qv[u];
        } else {
#pragma unroll
            for (int u = 0; u < U_; ++u) QCt[u][t - 160] = qv[u];
        }
    }
    __syncthreads();

    // ---- phase 3: build E chunks in LDS (overwrites Wt region with At) ----
    {   // At[c][r]: 32x128, 4 f4 per thread
        int col4 = (t & 31) * 4;
        int cb = t >> 5;
#pragma unroll
        for (int q = 0; q < 4; ++q) {
            int cq = cb + q * 8;
            int gc = c0 + cq;
            float s0 = 0, s1 = 0, s2 = 0, s3v = 0;
#pragma unroll
            for (int u = 0; u < U_; ++u) {
                float cv = QCt[u][cq];
                float4 a = *(const float4*)&QAt[u][col4];
                s0 += a.x * cv; s1 += a.y * cv; s2 += a.z * cv; s3v += a.w * cv;
            }
            float4 r4;
            r4.x = (col4 + 0 == gc) ? 0.f : __expf(s0 * INV9);
            r4.y = (col4 + 1 == gc) ? 0.f : __expf(s1 * INV9);
            r4.z = (col4 + 2 == gc) ? 0.f : __expf(s2 * INV9);
            r4.w = (col4 + 3 == gc) ? 0.f : __expf(s3v * INV9);
            *(float4*)&At[cq * 132 + col4] = r4;
        }
    }
    {   // Bs[c][κ]: 32x32, 1 f4 per thread
        int c = t >> 3;
        int k4 = (t & 7) * 4;
        int gc = c0 + c;
        float s0 = 0, s1 = 0, s2 = 0, s3v = 0;
#pragma unroll
        for (int u = 0; u < U_; ++u) {
            float cv = QCt[u][c];
            float4 kvec = *(const float4*)&QKt[u][k4];
            s0 += kvec.x * cv; s1 += kvec.y * cv; s2 += kvec.z * cv; s3v += kvec.w * cv;
        }
        float4 r4;
        r4.x = (kq0 + k4 + 0 == gc) ? 0.f : __expf(s0 * INV9);
        r4.y = (kq0 + k4 + 1 == gc) ? 0.f : __expf(s1 * INV9);
        r4.z = (kq0 + k4 + 2 == gc) ? 0.f : __expf(s2 * INV9);
        r4.w = (kq0 + k4 + 3 == gc) ? 0.f : __expf(s3v * INV9);
        *(float4*)&Bs[c][k4] = r4;
    }
    __syncthreads();

    // ---- phase 4: main contraction, 4x4 tile ----
    int r0 = (t >> 3) * 4;            // 32 row-groups (8-lane broadcast)
    int k0 = (t & 7) * 4;             // 8 κ-groups
    float acc[4][4] = {};
#pragma unroll 8
    for (int c = 0; c < 32; ++c) {
        float4 av = *(const float4*)&At[c * 132 + r0];
        float4 bv = *(const float4*)&Bs[c][k0];
        acc[0][0] += av.x * bv.x; acc[0][1] += av.x * bv.y;
        acc[0][2] += av.x * bv.z; acc[0][3] += av.x * bv.w;
        acc[1][0] += av.y * bv.x; acc[1][1] += av.y * bv.y;
        acc[1][2] += av.y * bv.z; acc[1][3] += av.y * bv.w;
        acc[2][0] += av.z * bv.x; acc[2][1] += av.z * bv.y;
        acc[2][2] += av.z * bv.z; acc[2][3] += av.z * bv.w;
        acc[3][0] += av.w * bv.x; acc[3][1] += av.w * bv.y;
        acc[3][2] += av.w * bv.z; acc[3][3] += av.w * bv.w;
    }

    // ---- phase 5: weight scores (rank-11) + combine ----
    float s3[4][4] = {};
#pragma unroll
    for (int u = 0; u < U_; ++u) {
        float4 av = *(const float4*)&QAt[u][r0];
        float4 kv = *(const float4*)&QKt[u][k0];
        s3[0][0] += av.x * kv.x; s3[0][1] += av.x * kv.y;
        s3[0][2] += av.x * kv.z; s3[0][3] += av.x * kv.w;
        s3[1][0] += av.y * kv.x; s3[1][1] += av.y * kv.y;
        s3[1][2] += av.y * kv.z; s3[1][3] += av.y * kv.w;
        s3[2][0] += av.z * kv.x; s3[2][1] += av.z * kv.y;
        s3[2][2] += av.z * kv.z; s3[2][3] += av.z * kv.w;
        s3[3][0] += av.w * kv.x; s3[3][1] += av.w * kv.y;
        s3[3][2] += av.w * kv.z; s3[3][3] += av.w * kv.w;
    }
    float rs[4] = {}, cs[4] = {};
#pragma unroll
    for (int x = 0; x < 4; ++x) {
#pragma unroll
        for (int y = 0; y < 4; ++y) {
            float w = ((r0 + x) == (kq0 + k0 + y)) ? 0.f : __expf(s3[x][y] * INV9);
            float v = w * acc[x][y];
            rs[x] += v; cs[y] += v;
        }
    }

    // ---- phase 6: row sums -> m1/m2 partial (reduce over 8 κ-lanes) ----
#pragma unroll
    for (int x = 0; x < 4; ++x) {
        rs[x] += __shfl_xor(rs[x], 1);
        rs[x] += __shfl_xor(rs[x], 2);
        rs[x] += __shfl_xor(rs[x], 4);
    }
    if ((t & 7) == 0) {
        float* MO = job ? m2p : m1p;
        size_t base = ((size_t)b * 16 + cc * 4 + kq) * S_ + r0;
#pragma unroll
        for (int x = 0; x < 4; ++x) MO[base + x] = rs[x];
    }

    // ---- phase 7: col sums -> m3 partial (job0 only) ----
    if (!job) {
#pragma unroll
        for (int y = 0; y < 4; ++y) {
            cs[y] += __shfl_xor(cs[y], 8);
            cs[y] += __shfl_xor(cs[y], 16);
            cs[y] += __shfl_xor(cs[y], 32);
        }
        __syncthreads();   // all At reads done; reuse pool as red[4][32]
        if ((t & 63) < 8) {
            int w = t >> 6;
            *(float4*)&red[w * 32 + k0] = make_float4(cs[0], cs[1], cs[2], cs[3]);
        }
        __syncthreads();
        if (t < 32)
            m3p[((size_t)b * 4 + cc) * S_ + kq0 + t] =
                red[t] + red[32 + t] + red[64 + t] + red[96 + t];
    }
}

// ---------------- Kernel 2: gather partials, normalize, V matmul ----------------
__global__ __launch_bounds__(128) void k_out(const float* __restrict__ m1p,
    const float* __restrict__ m2p, const float* __restrict__ m3p,
    const float* __restrict__ V, float* __restrict__ out) {
    int b = blockIdx.x, t = threadIdx.x;
    __shared__ float ms[3][S_];
    __shared__ float Vs[S_][33];
    __shared__ float zr[2];
    const float* Vb = V + (size_t)b * S_ * F_;
#pragma unroll
    for (int q = 0; q < 8; ++q) {
        int idx = t + q * 128;            // float4 idx 0..1023
        int row = idx >> 3, c4 = (idx & 7) * 4;
        float4 v = *(const float4*)&Vb[row * F_ + c4];
        Vs[row][c4 + 0] = v.x; Vs[row][c4 + 1] = v.y;
        Vs[row][c4 + 2] = v.z; Vs[row][c4 + 3] = v.w;
    }
    size_t b16 = (size_t)b * 16 * S_ + t;
    float v1 = 0.f, v2 = 0.f;
#pragma unroll
    for (int p = 0; p < 16; ++p) {
        v1 += m1p[b16 + p * S_];
        v2 += m2p[b16 + p * S_];
    }
    size_t b4 = (size_t)b * 4 * S_ + t;
    float v3 = m3p[b4] + m3p[b4 + S_] + m3p[b4 + 2 * S_] + m3p[b4 + 3 * S_];
    ms[0][t] = v1; ms[1][t] = v2; ms[2][t] = v3;
    float z = v1;
#pragma unroll
    for (int off = 32; off; off >>= 1) z += __shfl_xor(z, off);
    if ((t & 63) == 0) zr[t >> 6] = z;
    __syncthreads();
    float invZ = 1.0f / (zr[0] + zr[1]);
    if (t < 96) {
        int which = t >> 5, f = t & 31;
        const float* ml = &ms[which][0];
        float s = 0.f;
#pragma unroll 8
        for (int s0 = 0; s0 < S_; ++s0) s += ml[s0] * Vs[s0][f];
        out[(size_t)b * 96 + t] = s * invZ;
    }
}

extern "C" void kernel_launch(void* const* d_in, const int* in_sizes, int n_in,
                              void* d_out, int out_size, void* d_ws, size_t ws_size,
                              hipStream_t stream) {
    const float* X  = (const float*)d_in[0];
    const float* V  = (const float*)d_in[1];
    const float* W1 = (const float*)d_in[2];
    const float* b1 = (const float*)d_in[3];
    const float* W2 = (const float*)d_in[4];
    const float* b2 = (const float*)d_in[5];
    const float* W3 = (const float*)d_in[6];
    const float* b3 = (const float*)d_in[7];
    float* out = (float*)d_out;

    float* m1p = (float*)d_ws;                     // [B][16][S]
    float* m2p = m1p + (size_t)B_ * 16 * S_;       // [B][16][S]
    float* m3p = m2p + (size_t)B_ * 16 * S_;       // [B][4][S]

    k_fused<<<1024, 256, 0, stream>>>(X, W1, b1, W2, b2, W3, b3, m1p, m2p, m3p);
    k_out<<<B_, 128, 0, stream>>>(m1p, m2p, m3p, V, out);
}

// Round 6
// 24.548 us; speedup vs baseline: 1.4887x; 1.4887x over previous
//
#include <hip/hip_runtime.h>
#include <hip/hip_bf16.h>

// ThreeWayAttention: B=32, S=128, D=32, F=32, U=11
// p_ijk ∝ EA[i,j]·EB[j,k]·EC[i,k], EX = exp(X/9), diagonals = 0.
// Per block (b, job, cc=c-chunk of 32, kh=κ-half of 64):
//   job0: acc[i,κ]=Σ_{j∈cc} EA[i,j]EB[j,κ]; v=EC[i,κ]·acc → m1 part (row sums),
//         m3 part (col sums)
//   job1: acc[j,κ]=Σ_{i∈cc} EA[i,j]EC[i,κ]; v=EB[j,κ]·acc → m2 part (row sums)
// Unified: At[c][r] = exp(dot(QA[r],QC[c])/9)   (0 if r==c0+c)
//          Bs[c][κ] = exp(dot(QC[c],QK[κ])/9)   (0 if kk0+κ==c0+c)
//          W[r][κ]  = exp(dot(QA[r],QK[κ])/9)   (0 if r==kk0+κ)
// job0: QA=Q1, QC=Q2, QK=Q3.  job1: QA=Q2, QC=Q1, QK=Q3.
// out = [m1@V, m2@V, m3@V]/Z, Z = Σ m1.

#define B_ 32
#define S_ 128
#define D_ 32
#define F_ 32
#define U_ 11
#define INV9 (1.0f / 9.0f)

__global__ __launch_bounds__(256, 2) void k_fused(
    const float* __restrict__ X,
    const float* __restrict__ W1, const float* __restrict__ b1,
    const float* __restrict__ W2, const float* __restrict__ b2,
    const float* __restrict__ W3, const float* __restrict__ b3,
    float* __restrict__ m1p, float* __restrict__ m2p, float* __restrict__ m3p) {
    int bid = blockIdx.x;
    int b   = bid & 31;
    int job = (bid >> 5) & 1;
    int cc  = (bid >> 6) & 3;
    int kh  = bid >> 8;                // 0..1
    int c0  = cc * 32, kk0 = kh * 64;
    int t = threadIdx.x;

    // pool aliases: Wt[3][U_][32] (1056 fl) -> At[32][132] -> red[4][64]
    __shared__ float pool[32 * 132];
    __shared__ float Bs[32][68];
    __shared__ float QAt[U_][S_];
    __shared__ float QKt[U_][64];
    __shared__ float QCt[U_][32];
    __shared__ float bsh[3][U_];
    float* At = pool;
    float* Wt = pool;
    float* red = pool;

    // ---- phase 1: stage W^T + biases ----
    for (int idx = t; idx < 3 * U_ * D_; idx += 256) {
        int m = idx / (U_ * D_), r = idx - m * (U_ * D_);
        int u = r >> 5, d = r & 31;
        const float* Wm = (m == 0) ? W1 : (m == 1) ? W2 : W3;
        Wt[idx] = Wm[d * U_ + u];
    }
    if (t < 3 * U_) {
        int m = t / U_, u = t - m * U_;
        const float* bm = (m == 0) ? b1 : (m == 1) ? b2 : b3;
        bsh[m][u] = bm[u];
    }
    __syncthreads();

    // ---- phase 2: Q projections (wave-uniform groups) ----
    // waves 0-1 (t<128): QA all 128 rows. wave 2 (128..191): QK 64 rows (kh
    // half). wave 3 lower half (192..223): QC 32 rows (cc chunk).
    if (t < 224) {
        int grp = (t < 128) ? 0 : (t < 192) ? 1 : 2;
        int row = (grp == 0) ? t : (grp == 1) ? (kk0 + t - 128) : (c0 + t - 192);
        int mat = (grp == 0) ? job : (grp == 1) ? 2 : (1 - job);
        const float* Xrow = X + ((size_t)b * S_ + row) * D_;
        float4 xv[8];
#pragma unroll
        for (int q = 0; q < 8; ++q) xv[q] = ((const float4*)Xrow)[q];
        float qv[U_];
#pragma unroll
        for (int u = 0; u < U_; ++u) qv[u] = bsh[mat][u];
#pragma unroll
        for (int d4 = 0; d4 < 8; ++d4) {
            float4 x = xv[d4];
#pragma unroll
            for (int u = 0; u < U_; ++u) {
                float4 w = *(const float4*)&Wt[(mat * U_ + u) * 32 + d4 * 4];
                qv[u] += x.x * w.x + x.y * w.y + x.z * w.z + x.w * w.w;
            }
        }
        if (grp == 0) {
#pragma unroll
            for (int u = 0; u < U_; ++u) QAt[u][t] = qv[u];
        } else if (grp == 1) {
#pragma unroll
            for (int u = 0; u < U_; ++u) QKt[u][t - 128] = qv[u];
        } else {
#pragma unroll
            for (int u = 0; u < U_; ++u) QCt[u][t - 192] = qv[u];
        }
    }
    __syncthreads();

    // ---- phase 3: build E chunks in LDS (At overwrites Wt region) ----
    {   // At[c][r]: 32x128
        int col4 = (t & 31) * 4;
        int cb = t >> 5;
#pragma unroll
        for (int q = 0; q < 4; ++q) {
            int cq = cb + q * 8;
            int gc = c0 + cq;
            float s0 = 0, s1 = 0, s2 = 0, s3v = 0;
#pragma unroll
            for (int u = 0; u < U_; ++u) {
                float cv = QCt[u][cq];
                float4 a = *(const float4*)&QAt[u][col4];
                s0 += a.x * cv; s1 += a.y * cv; s2 += a.z * cv; s3v += a.w * cv;
            }
            float4 r4;
            r4.x = (col4 + 0 == gc) ? 0.f : __expf(s0 * INV9);
            r4.y = (col4 + 1 == gc) ? 0.f : __expf(s1 * INV9);
            r4.z = (col4 + 2 == gc) ? 0.f : __expf(s2 * INV9);
            r4.w = (col4 + 3 == gc) ? 0.f : __expf(s3v * INV9);
            *(float4*)&At[cq * 132 + col4] = r4;
        }
    }
    {   // Bs[c][κ]: 32x64
#pragma unroll
        for (int q = 0; q < 2; ++q) {
            int idx = t + q * 256;           // f4 idx 0..511
            int c = idx >> 4;                // 0..31
            int k4 = (idx & 15) * 4;         // 0..60
            int gc = c0 + c;
            float s0 = 0, s1 = 0, s2 = 0, s3v = 0;
#pragma unroll
            for (int u = 0; u < U_; ++u) {
                float cv = QCt[u][c];
                float4 kvec = *(const float4*)&QKt[u][k4];
                s0 += kvec.x * cv; s1 += kvec.y * cv;
                s2 += kvec.z * cv; s3v += kvec.w * cv;
            }
            float4 r4;
            r4.x = (kk0 + k4 + 0 == gc) ? 0.f : __expf(s0 * INV9);
            r4.y = (kk0 + k4 + 1 == gc) ? 0.f : __expf(s1 * INV9);
            r4.z = (kk0 + k4 + 2 == gc) ? 0.f : __expf(s2 * INV9);
            r4.w = (kk0 + k4 + 3 == gc) ? 0.f : __expf(s3v * INV9);
            *(float4*)&Bs[c][k4] = r4;
        }
    }
    __syncthreads();

    // ---- phase 4: main contraction, 8x4 tile ----
    // r0 slow-index (4 addrs/wave @32B stride: conflict-free),
    // k0 fast-index (16 consecutive b128: conflict-free).
    int r0 = (t >> 4) * 8;                 // 128 rows
    int k0 = (t & 15) * 4;                 // 64 κ
    float acc[8][4] = {};
#pragma unroll 8
    for (int c = 0; c < 32; ++c) {
        float4 a0 = *(const float4*)&At[c * 132 + r0];
        float4 a1 = *(const float4*)&At[c * 132 + r0 + 4];
        float4 bv = *(const float4*)&Bs[c][k0];
        float av[8] = {a0.x, a0.y, a0.z, a0.w, a1.x, a1.y, a1.z, a1.w};
#pragma unroll
        for (int x = 0; x < 8; ++x) {
            acc[x][0] += av[x] * bv.x; acc[x][1] += av[x] * bv.y;
            acc[x][2] += av[x] * bv.z; acc[x][3] += av[x] * bv.w;
        }
    }

    // ---- phase 5: weight scores (rank-11) + combine ----
    float s3[8][4] = {};
#pragma unroll
    for (int u = 0; u < U_; ++u) {
        float4 a0 = *(const float4*)&QAt[u][r0];
        float4 a1 = *(const float4*)&QAt[u][r0 + 4];
        float4 kv = *(const float4*)&QKt[u][k0];
        float av[8] = {a0.x, a0.y, a0.z, a0.w, a1.x, a1.y, a1.z, a1.w};
#pragma unroll
        for (int x = 0; x < 8; ++x) {
            s3[x][0] += av[x] * kv.x; s3[x][1] += av[x] * kv.y;
            s3[x][2] += av[x] * kv.z; s3[x][3] += av[x] * kv.w;
        }
    }
    float rs[8] = {}, cs[4] = {};
#pragma unroll
    for (int x = 0; x < 8; ++x) {
#pragma unroll
        for (int y = 0; y < 4; ++y) {
            float w = ((r0 + x) == (kk0 + k0 + y)) ? 0.f : __expf(s3[x][y] * INV9);
            float v = w * acc[x][y];
            rs[x] += v; cs[y] += v;
        }
    }

    // ---- phase 6: row sums -> m1/m2 partial (reduce over 16 κ-lanes) ----
#pragma unroll
    for (int x = 0; x < 8; ++x) {
        rs[x] += __shfl_xor(rs[x], 1);
        rs[x] += __shfl_xor(rs[x], 2);
        rs[x] += __shfl_xor(rs[x], 4);
        rs[x] += __shfl_xor(rs[x], 8);
    }
    if ((t & 15) == 0) {
        float* MO = job ? m2p : m1p;
        size_t base = ((size_t)b * 8 + cc * 2 + kh) * S_ + r0;
#pragma unroll
        for (int x = 0; x < 8; ++x) MO[base + x] = rs[x];
    }

    // ---- phase 7: col sums -> m3 partial (job0 only) ----
    if (!job) {
#pragma unroll
        for (int y = 0; y < 4; ++y) {
            cs[y] += __shfl_xor(cs[y], 16);
            cs[y] += __shfl_xor(cs[y], 32);
        }
        __syncthreads();   // all At reads done; reuse pool as red[4][64]
        if ((t & 63) < 16) {
            int w = t >> 6;
            *(float4*)&red[w * 64 + k0] = make_float4(cs[0], cs[1], cs[2], cs[3]);
        }
        __syncthreads();
        if (t < 64)
            m3p[((size_t)b * 4 + cc) * S_ + kk0 + t] =
                red[t] + red[64 + t] + red[128 + t] + red[192 + t];
    }
}

// ---------------- Kernel 2: gather partials, normalize, V matmul ----------------
__global__ __launch_bounds__(128) void k_out(const float* __restrict__ m1p,
    const float* __restrict__ m2p, const float* __restrict__ m3p,
    const float* __restrict__ V, float* __restrict__ out) {
    int b = blockIdx.x, t = threadIdx.x;
    __shared__ float ms[3][S_];
    __shared__ float Vs[S_][33];
    __shared__ float zr[2];
    const float* Vb = V + (size_t)b * S_ * F_;
#pragma unroll
    for (int q = 0; q < 8; ++q) {
        int idx = t + q * 128;            // float4 idx 0..1023
        int row = idx >> 3, c4 = (idx & 7) * 4;
        float4 v = *(const float4*)&Vb[row * F_ + c4];
        Vs[row][c4 + 0] = v.x; Vs[row][c4 + 1] = v.y;
        Vs[row][c4 + 2] = v.z; Vs[row][c4 + 3] = v.w;
    }
    size_t b8 = (size_t)b * 8 * S_ + t;
    float v1 = 0.f, v2 = 0.f;
#pragma unroll
    for (int p = 0; p < 8; ++p) {
        v1 += m1p[b8 + p * S_];
        v2 += m2p[b8 + p * S_];
    }
    size_t b4 = (size_t)b * 4 * S_ + t;
    float v3 = m3p[b4] + m3p[b4 + S_] + m3p[b4 + 2 * S_] + m3p[b4 + 3 * S_];
    ms[0][t] = v1; ms[1][t] = v2; ms[2][t] = v3;
    float z = v1;
#pragma unroll
    for (int off = 32; off; off >>= 1) z += __shfl_xor(z, off);
    if ((t & 63) == 0) zr[t >> 6] = z;
    __syncthreads();
    float invZ = 1.0f / (zr[0] + zr[1]);
    if (t < 96) {
        int which = t >> 5, f = t & 31;
        const float* ml = &ms[which][0];
        float s = 0.f;
#pragma unroll 8
        for (int s0 = 0; s0 < S_; ++s0) s += ml[s0] * Vs[s0][f];
        out[(size_t)b * 96 + t] = s * invZ;
    }
}

extern "C" void kernel_launch(void* const* d_in, const int* in_sizes, int n_in,
                              void* d_out, int out_size, void* d_ws, size_t ws_size,
                              hipStream_t stream) {
    const float* X  = (const float*)d_in[0];
    const float* V  = (const float*)d_in[1];
    const float* W1 = (const float*)d_in[2];
    const float* b1 = (const float*)d_in[3];
    const float* W2 = (const float*)d_in[4];
    const float* b2 = (const float*)d_in[5];
    const float* W3 = (const float*)d_in[6];
    const float* b3 = (const float*)d_in[7];
    float* out = (float*)d_out;

    float* m1p = (float*)d_ws;                     // [B][8][S]
    float* m2p = m1p + (size_t)B_ * 8 * S_;        // [B][8][S]
    float* m3p = m2p + (size_t)B_ * 8 * S_;        // [B][4][S]

    k_fused<<<512, 256, 0, stream>>>(X, W1, b1, W2, b2, W3, b3, m1p, m2p, m3p);
    k_out<<<B_, 128, 0, stream>>>(m1p, m2p, m3p, V, out);
}

// Round 7
// 23.953 us; speedup vs baseline: 1.5256x; 1.0248x over previous
//
#include <hip/hip_runtime.h>
#include <hip/hip_bf16.h>

// ThreeWayAttention: B=32, S=128, D=32, F=32, U=11
// p_ijk ∝ EA[i,j]·EB[j,k]·EC[i,k], EX = exp(X/9), diagonals = 0.
// E computed ONCE in k_qe (global, 6.3 MB, L2/L3-resident).
// k_marg per block (b, job, cc=c-chunk of 16, kh=κ-half of 64):
//   job0: acc[i,κ]=Σ_{j∈cc} EA[i,j]EB[j,κ]; v=EC[i,κ]·acc → m1 part (rows),
//         m3 part (cols).  At[j][i]=EA[i][j] (LDS transpose), Bs=EB, W=EC.
//   job1: acc[j,κ]=Σ_{i∈cc} EA[i,j]EC[i,κ]; v=EB[j,κ]·acc → m2 part (rows).
//         At[i][j]=EA[i][j] (natural), Bs=EC, W=EB.
// out = [m1@V, m2@V, m3@V]/Z, Z = Σ m1.

#define B_ 32
#define S_ 128
#define D_ 32
#define F_ 32
#define U_ 11
#define INV9 (1.0f / 9.0f)

// ---------------- Kernel 1: Q projections + E tiles (once) ----------------
// grid: B*3*4 blocks (b, m, i-tile of 32 rows), 256 threads.
__global__ __launch_bounds__(256) void k_qe(const float* __restrict__ X,
    const float* __restrict__ W1, const float* __restrict__ b1,
    const float* __restrict__ W2, const float* __restrict__ b2,
    const float* __restrict__ W3, const float* __restrict__ b3,
    float* __restrict__ E) {
    int blk = blockIdx.x;
    int b = blk / 12;
    int rest = blk - b * 12;
    int m = rest >> 2;   // 0:EA(Q1,Q2) 1:EB(Q2,Q3) 2:EC(Q1,Q3)
    int tl = rest & 3;   // 32-row tile
    __shared__ float Xs[S_][D_ + 1];
    __shared__ float QR[S_][13];
    __shared__ float QL[32][13];
    __shared__ float Ws[2][D_][U_];
    __shared__ float bsh[2][U_];
    int t = threadIdx.x;

    const float* Xb = X + (size_t)b * S_ * D_;
    for (int idx = t; idx < S_ * D_; idx += 256) Xs[idx >> 5][idx & 31] = Xb[idx];
    const float* WL = (m == 0) ? W1 : (m == 1) ? W2 : W1;
    const float* WR = (m == 0) ? W2 : (m == 1) ? W3 : W3;
    const float* bL = (m == 0) ? b1 : (m == 1) ? b2 : b1;
    const float* bR = (m == 0) ? b2 : (m == 1) ? b3 : b3;
    for (int idx = t; idx < D_ * U_; idx += 256) {
        Ws[0][idx / U_][idx % U_] = WL[idx];
        Ws[1][idx / U_][idx % U_] = WR[idx];
    }
    if (t < U_) { bsh[0][t] = bL[t]; bsh[1][t] = bR[t]; }
    __syncthreads();

    if (t < 160) {
        int isR = (t < 128);
        int side = isR ? 1 : 0;
        int row = isR ? t : (tl * 32 + (t - 128));
        float q[U_];
#pragma unroll
        for (int u = 0; u < U_; ++u) q[u] = bsh[side][u];
#pragma unroll
        for (int d = 0; d < D_; ++d) {
            float x = Xs[row][d];
#pragma unroll
            for (int u = 0; u < U_; ++u) q[u] += x * Ws[side][d][u];
        }
        float* dst = isR ? &QR[t][0] : &QL[t - 128][0];
#pragma unroll
        for (int u = 0; u < U_; ++u) dst[u] = q[u];
    }
    __syncthreads();

    float* Eb = E + (size_t)(b * 3 + m) * (S_ * S_);
    for (int idx = t; idx < 32 * S_; idx += 256) {
        int il = idx >> 7, j = idx & 127;
        int i = tl * 32 + il;
        float s = 0.f;
#pragma unroll
        for (int u = 0; u < U_; ++u) s += QL[il][u] * QR[j][u];
        Eb[i * S_ + j] = (i == j) ? 0.f : __expf(s * INV9);
    }
}

// ---------------- Kernel 2: marginals (exp-free, high-occupancy) ----------------
// grid: 1024 = kh*512 + cc*64 + job*32 + b, 256 threads, 8x4 tile.
__global__ __launch_bounds__(256, 4) void k_marg(const float* __restrict__ E,
    float* __restrict__ m1p, float* __restrict__ m2p, float* __restrict__ m3p) {
    int bid = blockIdx.x;
    int b   = bid & 31;
    int job = (bid >> 5) & 1;
    int cc  = (bid >> 6) & 7;          // 8 chunks of 16
    int kh  = bid >> 9;                // 0..1
    int c0  = cc * 16, kk0 = kh * 64;
    const float* EA = E + (size_t)b * 3 * S_ * S_;
    const float* EB = EA + S_ * S_;
    const float* EC = EB + S_ * S_;
    const float* Bsrc = job ? EC : EB;
    const float* Wsrc = job ? EB : EC;

    __shared__ float At[16][132];      // [c][r]
    __shared__ float Bs[16][68];       // [c][κ]
    float* red = &At[0][0];            // alias for m3 cross-wave reduce [4][64]

    int t = threadIdx.x;

    // ---- stage At ----
    if (job == 0) {
        // At[j][i] = EA[i][c0+j] (transpose in LDS; 2-way write conflict = free)
#pragma unroll
        for (int q = 0; q < 2; ++q) {
            int idx = t + q * 256;            // f4 idx 0..511
            int i = idx >> 2;                 // 0..127
            int j4 = (idx & 3) * 4;           // 0..12
            float4 v = *(const float4*)&EA[(size_t)i * S_ + c0 + j4];
            At[j4 + 0][i] = v.x; At[j4 + 1][i] = v.y;
            At[j4 + 2][i] = v.z; At[j4 + 3][i] = v.w;
        }
    } else {
        // At[i][j] = EA[c0+i][j] (natural rows)
#pragma unroll
        for (int q = 0; q < 2; ++q) {
            int idx = t + q * 256;
            int cl = idx >> 5;                // 0..15
            int col4 = (idx & 31) * 4;        // 0..124
            *(float4*)&At[cl][col4] =
                *(const float4*)&EA[(size_t)(c0 + cl) * S_ + col4];
        }
    }
    // ---- stage Bs ----
    {
        int cl = t >> 4;                      // 0..15
        int k4 = (t & 15) * 4;                // 0..60
        *(float4*)&Bs[cl][k4] =
            *(const float4*)&Bsrc[(size_t)(c0 + cl) * S_ + kk0 + k4];
    }
    __syncthreads();

    // ---- main contraction: 8x4 tile, 16 c-iters ----
    int r0 = (t >> 4) * 8;                    // 128 rows
    int k0 = (t & 15) * 4;                    // 64 κ
    float acc[8][4] = {};
#pragma unroll
    for (int c = 0; c < 16; ++c) {
        float4 a0 = *(const float4*)&At[c][r0];
        float4 a1 = *(const float4*)&At[c][r0 + 4];
        float4 bv = *(const float4*)&Bs[c][k0];
        float av[8] = {a0.x, a0.y, a0.z, a0.w, a1.x, a1.y, a1.z, a1.w};
#pragma unroll
        for (int x = 0; x < 8; ++x) {
            acc[x][0] += av[x] * bv.x; acc[x][1] += av[x] * bv.y;
            acc[x][2] += av[x] * bv.z; acc[x][3] += av[x] * bv.w;
        }
    }

    // ---- epilogue: weight from global E, row/col sums ----
    float rs[8], cs[4] = {0.f, 0.f, 0.f, 0.f};
#pragma unroll
    for (int x = 0; x < 8; ++x) {
        float4 w = *(const float4*)&Wsrc[(size_t)(r0 + x) * S_ + kk0 + k0];
        float v0 = w.x * acc[x][0], v1 = w.y * acc[x][1];
        float v2 = w.z * acc[x][2], v3 = w.w * acc[x][3];
        rs[x] = v0 + v1 + v2 + v3;
        cs[0] += v0; cs[1] += v1; cs[2] += v2; cs[3] += v3;
    }
    // row sums -> m1/m2 partial (reduce over 16 κ-lane-groups)
#pragma unroll
    for (int x = 0; x < 8; ++x) {
        rs[x] += __shfl_xor(rs[x], 1);
        rs[x] += __shfl_xor(rs[x], 2);
        rs[x] += __shfl_xor(rs[x], 4);
        rs[x] += __shfl_xor(rs[x], 8);
    }
    if ((t & 15) == 0) {
        float* MO = job ? m2p : m1p;
        size_t base = ((size_t)b * 16 + cc * 2 + kh) * S_ + r0;
#pragma unroll
        for (int x = 0; x < 8; ++x) MO[base + x] = rs[x];
    }
    // col sums -> m3 partial (job0 only)
    if (!job) {
#pragma unroll
        for (int y = 0; y < 4; ++y) {
            cs[y] += __shfl_xor(cs[y], 16);
            cs[y] += __shfl_xor(cs[y], 32);
        }
        __syncthreads();                      // At reads done; reuse as red[4][64]
        if ((t & 63) < 16) {
            int w = t >> 6;
            *(float4*)&red[w * 64 + k0] = make_float4(cs[0], cs[1], cs[2], cs[3]);
        }
        __syncthreads();
        if (t < 64)
            m3p[((size_t)b * 8 + cc) * S_ + kk0 + t] =
                red[t] + red[64 + t] + red[128 + t] + red[192 + t];
    }
}

// ---------------- Kernel 3: gather partials, normalize, V matmul ----------------
__global__ __launch_bounds__(128) void k_out(const float* __restrict__ m1p,
    const float* __restrict__ m2p, const float* __restrict__ m3p,
    const float* __restrict__ V, float* __restrict__ out) {
    int b = blockIdx.x, t = threadIdx.x;
    __shared__ float ms[3][S_];
    __shared__ float Vs[S_][33];
    __shared__ float zr[2];
    const float* Vb = V + (size_t)b * S_ * F_;
#pragma unroll
    for (int q = 0; q < 8; ++q) {
        int idx = t + q * 128;            // float4 idx 0..1023
        int row = idx >> 3, c4 = (idx & 7) * 4;
        float4 v = *(const float4*)&Vb[row * F_ + c4];
        Vs[row][c4 + 0] = v.x; Vs[row][c4 + 1] = v.y;
        Vs[row][c4 + 2] = v.z; Vs[row][c4 + 3] = v.w;
    }
    size_t b16 = (size_t)b * 16 * S_ + t;
    float v1 = 0.f, v2 = 0.f;
#pragma unroll
    for (int p = 0; p < 16; ++p) {
        v1 += m1p[b16 + p * S_];
        v2 += m2p[b16 + p * S_];
    }
    size_t b8 = (size_t)b * 8 * S_ + t;
    float v3 = 0.f;
#pragma unroll
    for (int p = 0; p < 8; ++p) v3 += m3p[b8 + p * S_];
    ms[0][t] = v1; ms[1][t] = v2; ms[2][t] = v3;
    float z = v1;
#pragma unroll
    for (int off = 32; off; off >>= 1) z += __shfl_xor(z, off);
    if ((t & 63) == 0) zr[t >> 6] = z;
    __syncthreads();
    float invZ = 1.0f / (zr[0] + zr[1]);
    if (t < 96) {
        int which = t >> 5, f = t & 31;
        const float* ml = &ms[which][0];
        float s = 0.f;
#pragma unroll 8
        for (int s0 = 0; s0 < S_; ++s0) s += ml[s0] * Vs[s0][f];
        out[(size_t)b * 96 + t] = s * invZ;
    }
}

extern "C" void kernel_launch(void* const* d_in, const int* in_sizes, int n_in,
                              void* d_out, int out_size, void* d_ws, size_t ws_size,
                              hipStream_t stream) {
    const float* X  = (const float*)d_in[0];
    const float* V  = (const float*)d_in[1];
    const float* W1 = (const float*)d_in[2];
    const float* b1 = (const float*)d_in[3];
    const float* W2 = (const float*)d_in[4];
    const float* b2 = (const float*)d_in[5];
    const float* W3 = (const float*)d_in[6];
    const float* b3 = (const float*)d_in[7];
    float* out = (float*)d_out;

    float* E   = (float*)d_ws;                     // [B][3][S][S]
    float* m1p = E + (size_t)B_ * 3 * S_ * S_;     // [B][16][S]
    float* m2p = m1p + (size_t)B_ * 16 * S_;       // [B][16][S]
    float* m3p = m2p + (size_t)B_ * 16 * S_;       // [B][8][S]

    k_qe<<<B_ * 12, 256, 0, stream>>>(X, W1, b1, W2, b2, W3, b3, E);
    k_marg<<<1024, 256, 0, stream>>>(E, m1p, m2p, m3p);
    k_out<<<B_, 128, 0, stream>>>(m1p, m2p, m3p, V, out);
}